// Round 12
// baseline (457.867 us; speedup 1.0000x reference)
//
#include <hip/hip_runtime.h>

#define NUM_CATEGORIES 64
#define IN_DIM 1024
#define OUT_DIM 1024
#define BATCH 32
#define SEQ 512

#define BM 256
#define BN 256
#define BK 32
#define NSTEP (IN_DIM / BK)   // 32

#define LDA 40     // bf16 elems per A row (64B data + 16B pad)
#define LDBW 260   // u32 words per B k-pair row (256 data + 4 pad)

typedef float f32x4 __attribute__((ext_vector_type(4)));
typedef float f32x2 __attribute__((ext_vector_type(2)));
typedef unsigned int u32x4 __attribute__((ext_vector_type(4)));
typedef __bf16 bf16x2 __attribute__((ext_vector_type(2)));
typedef __bf16 bf16x4 __attribute__((ext_vector_type(4)));
typedef __bf16 bf16x8 __attribute__((ext_vector_type(8)));

// 12 waves: 8 consumers (MFMA only in K-loop) + 4 producers (loads+cvt+ds_write
// only). Role diversity breaks the all-waves-lockstep stall that pinned
// R5..R11 at 51-58us. 3 waves/SIMD via launch_bounds cap (consumer ~164 VGPR).
__global__ __launch_bounds__(768, 3)
void cslinear_kernel(const float* __restrict__ x,
                     const int* __restrict__ cid,
                     const float* __restrict__ weight,
                     const float* __restrict__ bias,
                     float* __restrict__ out) {
    __shared__ unsigned short As[2][BM * LDA];          // 2 x 20 KB
    __shared__ unsigned int   Bs[2][(BK / 2) * LDBW];   // 2 x 16.25 KB

    const int t    = threadIdx.x;
    const int lane = t & 63;
    const int w    = t >> 6;            // 0..11
    const bool consumer = (w < 8);
    const int pt   = t - 512;           // producer thread id 0..255 (valid if !consumer)

    // XCD-aware remap: slot s -> XCD s%8; each XCD owns 4 whole batches.
    const int s    = blockIdx.x;        // 0..255
    const int xcd  = s & 7;
    const int ixd  = s >> 3;            // 0..31
    const int b    = xcd + 8 * (ixd >> 3);
    const int j    = ixd & 7;
    const int nt   = j & 3;             // 0..3
    const int mt   = j >> 2;            // 0..1

    const int c = cid[b];
    const float* Wp = weight + (size_t)c * IN_DIM * OUT_DIM + (size_t)nt * BN;
    const float* Xp = x + ((size_t)b * SEQ + (size_t)mt * BM) * IN_DIM;
    float* Op = out + ((size_t)b * SEQ + (size_t)mt * BM) * OUT_DIM + (size_t)nt * BN;

    f32x4 acc[8][4] = {};               // consumer: wave tile 128(m) x 64(n)

    const int mbase = (w >> 2) * 128;   // consumer decomposition (w 0..7)
    const int nbase = (w & 3) * 64;
    const int lrow  = lane & 15;
    const int lhi   = lane >> 4;

    // producer staging regs, 1-deep (full-step in-flight window >> HBM latency)
    f32x4 ra[8];                        // A: 256x32 f32 / 256 lanes = 8 f32x4
    f32x4 rb0[4], rb1[4];               // B: 32x256 f32 / 256 lanes = 4 units x 2 rows

    auto LOADT = [&](int ks) {          // producer only
        const float* Xk = Xp + ks * BK;
        #pragma unroll
        for (int i = 0; i < 8; ++i) {
            int f   = i * 256 + pt;     // 0..2047
            int row = f >> 3;           // 0..255
            int c4  = f & 7;            // 0..7
            ra[i] = *reinterpret_cast<const f32x4*>(Xk + (size_t)row * IN_DIM + c4 * 4);
        }
        const float* Wk = Wp + (size_t)(ks * BK) * OUT_DIM;
        #pragma unroll
        for (int i = 0; i < 4; ++i) {
            int u  = i * 256 + pt;      // 0..1023
            int kp = u >> 6;            // 0..15
            int n4 = u & 63;            // 0..63
            const float* bse = Wk + (size_t)(2 * kp) * OUT_DIM + n4 * 4;
            rb0[i] = *reinterpret_cast<const f32x4*>(bse);
            rb1[i] = *reinterpret_cast<const f32x4*>(bse + OUT_DIM);
        }
    };

    auto STORET = [&](int p) {          // producer only; v_cvt_pk_bf16_f32 packs
        char* AsB = reinterpret_cast<char*>(&As[p][0]);
        #pragma unroll
        for (int i = 0; i < 8; ++i) {
            int f   = i * 256 + pt;
            int row = f >> 3;
            int c4  = f & 7;
            bf16x4 a4 = __builtin_convertvector(ra[i], bf16x4);
            *reinterpret_cast<bf16x4*>(AsB + row * (LDA * 2) + c4 * 8) = a4;
        }
        unsigned int* BsW = &Bs[p][0];
        #pragma unroll
        for (int i = 0; i < 4; ++i) {
            int u  = i * 256 + pt;
            int kp = u >> 6;
            int n4 = u & 63;
            u32x4 q;
            #pragma unroll
            for (int jj = 0; jj < 4; ++jj) {
                f32x2 pr;
                pr.x = rb0[i][jj];      // k   (low 16)
                pr.y = rb1[i][jj];      // k+1 (high 16)
                bf16x2 pb = __builtin_convertvector(pr, bf16x2);
                q[jj] = __builtin_bit_cast(unsigned int, pb);
            }
            *reinterpret_cast<u32x4*>(BsW + kp * LDBW + n4 * 4) = q;
        }
    };

    auto COMPUTE = [&](int p) {         // consumer only
        const char* AsB = reinterpret_cast<const char*>(&As[p][0]);
        const unsigned int* BsW = &Bs[p][0];
        bf16x8 bfr[4];
        #pragma unroll
        for (int ni = 0; ni < 4; ++ni) {
            int n   = nbase + ni * 16 + lrow;
            int kp0 = lhi * 4;
            u32x4 wds;
            #pragma unroll
            for (int jj = 0; jj < 4; ++jj)
                wds[jj] = BsW[(kp0 + jj) * LDBW + n];
            bfr[ni] = __builtin_bit_cast(bf16x8, wds);
        }
        __builtin_amdgcn_s_setprio(1);  // T5: real role diversity now exists
        #pragma unroll
        for (int mi = 0; mi < 8; ++mi) {
            int r = mbase + mi * 16 + lrow;
            bf16x8 afr = *reinterpret_cast<const bf16x8*>(AsB + r * (LDA * 2) + lhi * 16);
            #pragma unroll
            for (int ni = 0; ni < 4; ++ni)
                acc[mi][ni] = __builtin_amdgcn_mfma_f32_16x16x32_bf16(
                    afr, bfr[ni], acc[mi][ni], 0, 0, 0);
        }
        __builtin_amdgcn_s_setprio(0);
    };

    // prologue: producers stage tile0 -> buf0 and put tile1 loads in flight
    if (!consumer) {
        LOADT(0);
        STORET(0);                      // compiler waits vmcnt on uses
        LOADT(1);
        asm volatile("s_waitcnt lgkmcnt(0)" ::: "memory");
    }
    __builtin_amdgcn_s_barrier();

    // K-loop: consumers read buf p; producers write buf p^1 (tile ks+1) and
    // issue loads for ks+2. Barrier per step orders write(p^1) before next
    // step's reads, and this step's reads of p before step ks+2's writes to p.
    for (int ks = 0; ks < NSTEP; ++ks) {
        const int p = ks & 1;
        if (consumer) {
            COMPUTE(p);                 // ds_reads lgkm-complete before MFMAs
        } else {
            if (ks + 1 < NSTEP) STORET(p ^ 1);   // regs from loads 1 step old
            if (ks + 2 < NSTEP) LOADT(ks + 2);   // refill regs (WAR-ordered)
            asm volatile("s_waitcnt lgkmcnt(0)" ::: "memory");
        }
        __builtin_amdgcn_s_barrier();
    }

    // epilogue: consumers only. C/D layout col=lane&15, row=(lane>>4)*4+reg
    if (consumer) {
        const int lcol  = lane & 15;
        const int lrow4 = (lane >> 4) * 4;
        float bv[4];
        #pragma unroll
        for (int ni = 0; ni < 4; ++ni)
            bv[ni] = bias[(size_t)c * OUT_DIM + nt * BN + nbase + ni * 16 + lcol];

        #pragma unroll
        for (int mi = 0; mi < 8; ++mi) {
            int rbase = mbase + mi * 16 + lrow4;
            #pragma unroll
            for (int ni = 0; ni < 4; ++ni) {
                int ncol = nbase + ni * 16 + lcol;
                #pragma unroll
                for (int r = 0; r < 4; ++r) {
                    Op[(size_t)(rbase + r) * OUT_DIM + ncol] = acc[mi][ni][r] + bv[ni];
                }
            }
        }
    }
}

extern "C" void kernel_launch(void* const* d_in, const int* in_sizes, int n_in,
                              void* d_out, int out_size, void* d_ws, size_t ws_size,
                              hipStream_t stream) {
    const float* x      = (const float*)d_in[0];
    const int*   cid    = (const int*)d_in[1];
    const float* weight = (const float*)d_in[2];
    const float* bias   = (const float*)d_in[3];
    float* out = (float*)d_out;

    dim3 grid(256);     // flat: XCD-aware remap inside kernel; 1 block/CU
    dim3 block(768);    // 8 consumer + 4 producer waves
    hipLaunchKernelGGL(cslinear_kernel, grid, block, 0, stream,
                       x, cid, weight, bias, out);
}

// Round 13
// 51.404 us; speedup vs baseline: 8.9072x; 8.9072x over previous
//
#include <hip/hip_runtime.h>
#include <type_traits>

#define NUM_CATEGORIES 64
#define IN_DIM 1024
#define OUT_DIM 1024
#define BATCH 32
#define SEQ 512

#define BM 256
#define BN 256
#define BK 32
#define NSTEP (IN_DIM / BK)   // 32

#define LDA 40     // bf16 elems per A row (64B data + 16B pad)
#define LDBW 260   // u32 words per B k-pair row (256 data + 4 pad)

typedef float f32x4 __attribute__((ext_vector_type(4)));
typedef float f32x2 __attribute__((ext_vector_type(2)));
typedef unsigned int u32x4 __attribute__((ext_vector_type(4)));
typedef __bf16 bf16x2 __attribute__((ext_vector_type(2)));
typedef __bf16 bf16x4 __attribute__((ext_vector_type(4)));
typedef __bf16 bf16x8 __attribute__((ext_vector_type(8)));

__global__ __launch_bounds__(512, 2)
void cslinear_kernel(const float* __restrict__ x,
                     const int* __restrict__ cid,
                     const float* __restrict__ weight,
                     const float* __restrict__ bias,
                     float* __restrict__ out) {
    __shared__ unsigned short As[2][BM * LDA];          // 2 x 20 KB
    __shared__ unsigned int   Bs[2][(BK / 2) * LDBW];   // 2 x 16.25 KB

    const int t    = threadIdx.x;
    const int lane = t & 63;
    const int w    = t >> 6;      // 0..7

    // XCD-aware remap: slot s -> XCD s%8; each XCD owns 4 whole batches.
    const int s    = blockIdx.x;      // 0..255
    const int xcd  = s & 7;
    const int ixd  = s >> 3;          // 0..31
    const int b    = xcd + 8 * (ixd >> 3);
    const int j    = ixd & 7;
    const int nt   = j & 3;           // 0..3
    const int mt   = j >> 2;          // 0..1

    const int c = cid[b];
    const float* Wp = weight + (size_t)c * IN_DIM * OUT_DIM + (size_t)nt * BN;
    const float* Xp = x + ((size_t)b * SEQ + (size_t)mt * BM) * IN_DIM;
    float* Op = out + ((size_t)b * SEQ + (size_t)mt * BM) * OUT_DIM + (size_t)nt * BN;

    f32x4 acc[8][4] = {};               // wave tile 128(m) x 64(n)

    const int mbase = (w >> 2) * 128;
    const int nbase = (w & 3) * 64;
    const int lrow  = lane & 15;
    const int lhi   = lane >> 4;

    // 2-deep staging sets, ALL indices compile-time (rule #20)
    f32x4 ra[2][4];
    f32x4 rb0[2][2], rb1[2][2];

    auto LOADT = [&](int ks, auto S) {
        constexpr int ss = decltype(S)::value;
        const float* Xk = Xp + ks * BK;
        #pragma unroll
        for (int i = 0; i < 4; ++i) {
            int f   = i * 512 + t;
            int row = f >> 3;
            int c4  = f & 7;
            ra[ss][i] = *reinterpret_cast<const f32x4*>(Xk + (size_t)row * IN_DIM + c4 * 4);
        }
        const float* Wk = Wp + (size_t)(ks * BK) * OUT_DIM;
        #pragma unroll
        for (int i = 0; i < 2; ++i) {
            int u  = i * 512 + t;
            int kp = u >> 6;
            int n4 = u & 63;
            const float* bse = Wk + (size_t)(2 * kp) * OUT_DIM + n4 * 4;
            rb0[ss][i] = *reinterpret_cast<const f32x4*>(bse);
            rb1[ss][i] = *reinterpret_cast<const f32x4*>(bse + OUT_DIM);
        }
    };

    // pack set ss -> LDS buffer ss (v_cvt_pk_bf16_f32 via native casts)
    auto STORET = [&](auto S) {
        constexpr int ss = decltype(S)::value;
        char* AsB = reinterpret_cast<char*>(&As[ss][0]);
        #pragma unroll
        for (int i = 0; i < 4; ++i) {
            int f   = i * 512 + t;
            int row = f >> 3;
            int c4  = f & 7;
            bf16x4 a4 = __builtin_convertvector(ra[ss][i], bf16x4);
            *reinterpret_cast<bf16x4*>(AsB + row * (LDA * 2) + c4 * 8) = a4;
        }
        unsigned int* BsW = &Bs[ss][0];
        #pragma unroll
        for (int i = 0; i < 2; ++i) {
            int u  = i * 512 + t;
            int kp = u >> 6;
            int n4 = u & 63;
            u32x4 q;
            #pragma unroll
            for (int jj = 0; jj < 4; ++jj) {
                f32x2 pr;
                pr.x = rb0[ss][i][jj];   // k   (low 16)
                pr.y = rb1[ss][i][jj];   // k+1 (high 16)
                bf16x2 pb = __builtin_convertvector(pr, bf16x2);
                q[jj] = __builtin_bit_cast(unsigned int, pb);
            }
            *reinterpret_cast<u32x4*>(BsW + kp * LDBW + n4 * 4) = q;
        }
    };

    auto COMPUTE = [&](auto S) {
        constexpr int ss = decltype(S)::value;
        const char* AsB = reinterpret_cast<const char*>(&As[ss][0]);
        const unsigned int* BsW = &Bs[ss][0];
        bf16x8 bfr[4];
        #pragma unroll
        for (int ni = 0; ni < 4; ++ni) {
            int n   = nbase + ni * 16 + lrow;
            int kp0 = lhi * 4;
            u32x4 wds;
            #pragma unroll
            for (int jj = 0; jj < 4; ++jj)
                wds[jj] = BsW[(kp0 + jj) * LDBW + n];
            bfr[ni] = __builtin_bit_cast(bf16x8, wds);
        }
        #pragma unroll
        for (int mi = 0; mi < 8; ++mi) {
            int r = mbase + mi * 16 + lrow;
            bf16x8 afr = *reinterpret_cast<const bf16x8*>(AsB + r * (LDA * 2) + lhi * 16);
            #pragma unroll
            for (int ni = 0; ni < 4; ++ni)
                acc[mi][ni] = __builtin_amdgcn_mfma_f32_16x16x32_bf16(
                    afr, bfr[ni], acc[mi][ni], 0, 0, 0);
        }
    };

    constexpr std::integral_constant<int, 0> S0{};
    constexpr std::integral_constant<int, 1> S1{};

    // prologue: tile0 -> buf0; tile1 loads in flight
    LOADT(0, S0);
    STORET(S0);
    LOADT(1, S1);
    asm volatile("s_waitcnt lgkmcnt(0)" ::: "memory");
    __builtin_amdgcn_s_barrier();

    // Region order (the change vs R9): STORET FIRST (its ds_writes' latency
    // hides under the following COMPUTE), loads issued next (fly across the
    // barrier), COMPUTE last; the pre-barrier lgkmcnt(0) then finds both the
    // reads (MFMA-forced) and the writes (issued ~1500cy earlier) complete.
    // Safety unchanged: region r writes buf p^1 only after barrier r-1, which
    // drained region r-1's reads of p^1.
    for (int ks = 0; ks < NSTEP; ks += 2) {
        // region ks: write buf1 (tile ks+1), read buf0 (tile ks)
        STORET(S1);                               // set S1 loads are 1 region old
        if (ks + 2 < NSTEP) LOADT(ks + 2, S0);    // refill set0
        COMPUTE(S0);
        asm volatile("s_waitcnt lgkmcnt(0)" ::: "memory");
        __builtin_amdgcn_s_barrier();

        // region ks+1: write buf0 (tile ks+2), read buf1 (tile ks+1)
        if (ks + 2 < NSTEP) STORET(S0);
        if (ks + 3 < NSTEP) LOADT(ks + 3, S1);
        COMPUTE(S1);
        if (ks + 2 < NSTEP) {
            asm volatile("s_waitcnt lgkmcnt(0)" ::: "memory");
            __builtin_amdgcn_s_barrier();
        }
    }

    // epilogue: C/D layout col=lane&15, row=(lane>>4)*4+reg
    const int lcol  = lane & 15;
    const int lrow4 = (lane >> 4) * 4;
    float bv[4];
    #pragma unroll
    for (int ni = 0; ni < 4; ++ni)
        bv[ni] = bias[(size_t)c * OUT_DIM + nt * BN + nbase + ni * 16 + lcol];

    #pragma unroll
    for (int mi = 0; mi < 8; ++mi) {
        int rbase = mbase + mi * 16 + lrow4;
        #pragma unroll
        for (int ni = 0; ni < 4; ++ni) {
            int ncol = nbase + ni * 16 + lcol;
            #pragma unroll
            for (int r = 0; r < 4; ++r) {
                Op[(size_t)(rbase + r) * OUT_DIM + ncol] = acc[mi][ni][r] + bv[ni];
            }
        }
    }
}

extern "C" void kernel_launch(void* const* d_in, const int* in_sizes, int n_in,
                              void* d_out, int out_size, void* d_ws, size_t ws_size,
                              hipStream_t stream) {
    const float* x      = (const float*)d_in[0];
    const int*   cid    = (const int*)d_in[1];
    const float* weight = (const float*)d_in[2];
    const float* bias   = (const float*)d_in[3];
    float* out = (float*)d_out;

    dim3 grid(256);     // flat: XCD-aware remap inside kernel; 1 block/CU
    dim3 block(512);
    hipLaunchKernelGGL(cslinear_kernel, grid, block, 0, stream,
                       x, cid, weight, bias, out);
}